// Round 3
// baseline (103.532 us; speedup 1.0000x reference)
//
#include <hip/hip_runtime.h>

// Problem constants (fixed by reference setup_inputs)
#define HW 262144    // 512*512 pixels per image
#define NB 8         // batch
#define NC 32        // channels
#define NK 8         // num classes (NUM_IDS)

// ws layout (floats) — every slot fully overwritten each launch, no init:
//   psum  [4096][8]  at     0  (32768)  per-(b,c,chunk) class channel sums
//   pcnt  [128][8]   at 32768  (1024)   per-(b,chunk) class counts
//   meansT[8][32][8] at 33792  (2048)   transposed: [b][c][k]
//   counts[8][8]     at 35840  (64)
//   pdist [2048][8]  at 35904  (16384)  per-(b,chunk) class dist sums
#define WS_PSUM 0
#define WS_PCNT 32768
#define WS_MT   33792
#define WS_CNT  35840
#define WS_PD   35904

typedef float f4 __attribute__((ext_vector_type(4)));

// ---------------------------------------------------------------------------
// Pass 1: per-class channel partial sums. One block = (image b, channel c,
// 16K-pixel chunk). Per-thread private LDS slots (stride 9: coprime with 32
// banks -> max 2-way aliasing, free). Block writes its own psum slot — no
// atomics. c==0 blocks additionally compute label counts (labels L2-hot).
// blockIdx layout: b = f&7 so XCD (heuristic f%8) owns one image -> label
// re-reads across the 32 channel-blocks of a chunk hit that XCD's L2.
// ---------------------------------------------------------------------------
__global__ __launch_bounds__(256) void k_pass1(const float* __restrict__ emb,
                                               const int* __restrict__ lab,
                                               float* __restrict__ ws) {
    __shared__ float slots[256 * 9];
    __shared__ float red[256];
    const int t = threadIdx.x;
    const int f = blockIdx.x;
    const int b = f & 7;
    const int o = f >> 3;        // 0..511 per image
    const int chunk = o >> 5;    // 0..15
    const int c = o & 31;

    float* myslot = &slots[t * 9];
#pragma unroll
    for (int i = 0; i < 9; ++i) myslot[i] = 0.f;

    const float* e = emb + ((size_t)(b * NC + c)) * HW;
    const int* lb = lab + (size_t)b * HW;
    const int base = chunk * 16384;

    for (int it = 0; it < 16; ++it) {
        const int p = base + it * 1024 + t * 4;
        const int4 l4 = *reinterpret_cast<const int4*>(lb + p);
        const f4 e4 = __builtin_nontemporal_load(reinterpret_cast<const f4*>(e + p));
        myslot[l4.x] += e4.x;
        myslot[l4.y] += e4.y;
        myslot[l4.z] += e4.z;
        myslot[l4.w] += e4.w;
    }
    __syncthreads();

    // reduce slots[256][8] -> 8 values
    {
        const int k = t & 7, r = t >> 3;  // r in 0..31
        float s = 0.f;
#pragma unroll
        for (int i = 0; i < 8; ++i) s += slots[(r + 32 * i) * 9 + k];
        red[r * 8 + k] = s;
    }
    __syncthreads();
    if (t < 8) {
        float s = 0.f;
#pragma unroll
        for (int r = 0; r < 32; ++r) s += red[r * 8 + t];
        ws[WS_PSUM + ((size_t)f) * 8 + t] = s;   // psum[(b,c,chunk)][k], f encodes it
    }

    // counts: only channel-0 blocks; labels re-read from L2
    if (c == 0) {
        __syncthreads();
#pragma unroll
        for (int i = 0; i < 9; ++i) myslot[i] = 0.f;
        for (int it = 0; it < 16; ++it) {
            const int p = base + it * 1024 + t * 4;
            const int4 l4 = *reinterpret_cast<const int4*>(lb + p);
            myslot[l4.x] += 1.f;
            myslot[l4.y] += 1.f;
            myslot[l4.z] += 1.f;
            myslot[l4.w] += 1.f;
        }
        __syncthreads();
        {
            const int k = t & 7, r = t >> 3;
            float s = 0.f;
#pragma unroll
            for (int i = 0; i < 8; ++i) s += slots[(r + 32 * i) * 9 + k];
            red[r * 8 + k] = s;
        }
        __syncthreads();
        if (t < 8) {
            float s = 0.f;
#pragma unroll
            for (int r = 0; r < 32; ++r) s += red[r * 8 + t];
            ws[WS_PCNT + (b * 16 + chunk) * 8 + t] = s;
        }
    }
}

// ---------------------------------------------------------------------------
// Reduce partials -> meansT [b][c][k] + counts [b][k]. grid 8 blocks (per b),
// 256 threads (t = c*8+k). Deterministic, no atomics.
// ---------------------------------------------------------------------------
__global__ __launch_bounds__(256) void k_means(float* __restrict__ ws) {
    const int b = blockIdx.x;
    const int t = threadIdx.x;
    const int c = t >> 3, k = t & 7;

    float cnt = 0.f;
#pragma unroll
    for (int ch = 0; ch < 16; ++ch) cnt += ws[WS_PCNT + (b * 16 + ch) * 8 + k];

    float s = 0.f;
    // psum index: f = b + 8*(c + 32*chunk)  ->  psum[f*8 + k]
#pragma unroll
    for (int ch = 0; ch < 16; ++ch) s += ws[WS_PSUM + ((size_t)(b + 8 * (c + 32 * ch))) * 8 + k];

    ws[WS_MT + b * 256 + c * 8 + k] = s / cnt;
    if (c == 0) ws[WS_CNT + b * 8 + k] = cnt;
}

// ---------------------------------------------------------------------------
// Pass 2: per-pixel distance to its class mean, segment-summed per class.
// One block = (image b, 1024-pixel chunk); 32-channel loop with means in LDS
// (transposed layout -> lanes hit 8 distinct banks, conflict-free).
// Block writes its own pdist slot — no atomics.
// ---------------------------------------------------------------------------
__global__ __launch_bounds__(256) void k_dist(const float* __restrict__ emb,
                                              const int* __restrict__ lab,
                                              float* __restrict__ ws) {
    __shared__ float mT[256];
    __shared__ float slots[256 * 9];
    __shared__ float red[256];
    const int t = threadIdx.x;
    const int f = blockIdx.x;
    const int b = f & 7;
    const int chunk = f >> 3;  // 0..255

    mT[t] = ws[WS_MT + b * 256 + t];
    float* myslot = &slots[t * 9];
#pragma unroll
    for (int i = 0; i < 9; ++i) myslot[i] = 0.f;
    __syncthreads();

    const int p = chunk * 1024 + t * 4;
    const int4 l4 = *reinterpret_cast<const int4*>(lab + (size_t)b * HW + p);
    const float* e = emb + (size_t)b * NC * HW + p;

    float a0 = 0.f, a1 = 0.f, a2 = 0.f, a3 = 0.f;
#pragma unroll 8
    for (int c = 0; c < NC; ++c) {
        const f4 e4 = __builtin_nontemporal_load(reinterpret_cast<const f4*>(e + (size_t)c * HW));
        const float* mrow = &mT[c * 8];
        float d0 = e4.x - mrow[l4.x];
        float d1 = e4.y - mrow[l4.y];
        float d2 = e4.z - mrow[l4.z];
        float d3 = e4.w - mrow[l4.w];
        a0 += d0 * d0;
        a1 += d1 * d1;
        a2 += d2 * d2;
        a3 += d3 * d3;
    }
    myslot[l4.x] += sqrtf(a0);
    myslot[l4.y] += sqrtf(a1);
    myslot[l4.z] += sqrtf(a2);
    myslot[l4.w] += sqrtf(a3);
    __syncthreads();

    {
        const int k = t & 7, r = t >> 3;
        float s = 0.f;
#pragma unroll
        for (int i = 0; i < 8; ++i) s += slots[(r + 32 * i) * 9 + k];
        red[r * 8 + k] = s;
    }
    __syncthreads();
    if (t < 8) {
        float s = 0.f;
#pragma unroll
        for (int r = 0; r < 32; ++r) s += red[r * 8 + t];
        ws[WS_PD + ((size_t)f) * 8 + t] = s;
    }
}

// ---------------------------------------------------------------------------
// Epilogue: reduce pdist partials; var loss + pairwise hinge among cluster
// means 1..7; average over images. One block, fully deterministic (no
// atomics: fixed-order LDS reductions).
// ---------------------------------------------------------------------------
__global__ __launch_bounds__(256) void k_final(const float* __restrict__ ws,
                                               float* __restrict__ out) {
    __shared__ float partial[256];
    __shared__ float distsum[64];   // [b][k]
    __shared__ float varl[8];
    __shared__ float hingeL[8 * 21];
    __shared__ float distl[8];
    const int t = threadIdx.x;

    // distsum[b][k] = sum over 256 chunks of pdist[(chunk*8+b)*8+k]
    // 4 threads per (b,k) pair, 64 chunks each. pdist addr = chunk*64 + p.
    {
        const int pidx = t >> 2;       // 0..63 == b*8+k
        const int sub = t & 3;
        float s = 0.f;
        for (int j = 0; j < 64; ++j)
            s += ws[WS_PD + (size_t)(j * 4 + sub) * 64 + pidx];
        partial[t] = s;
    }
    __syncthreads();
    if (t < 64)
        distsum[t] = partial[t * 4] + partial[t * 4 + 1] + partial[t * 4 + 2] + partial[t * 4 + 3];
    __syncthreads();

    // var loss per image: sum_{k=1..7} distsum[b][k] / counts[b][k]
    if (t < 8) {
        float v = 0.f;
#pragma unroll
        for (int k = 1; k < 8; ++k)
            v += distsum[t * 8 + k] / ws[WS_CNT + t * 8 + k];
        varl[t] = v;
    }

    // hinge: 8 images * 21 pairs among clusters 1..7
    if (t < 168) {
        const int b = t / 21;
        const int pr = t - b * 21;
        int ii = 1, jj = 2, cnt = 0;
        for (int a = 1; a <= 7; ++a)
            for (int bb = a + 1; bb <= 7; ++bb) {
                if (cnt == pr) { ii = a; jj = bb; }
                ++cnt;
            }
        const float* mTb = ws + WS_MT + b * 256;
        float sq = 0.f;
#pragma unroll
        for (int c = 0; c < NC; ++c) {
            const float d = mTb[c * 8 + ii] - mTb[c * 8 + jj];
            sq += d * d;
        }
        const float dist = sqrtf(sq);
        const float gap = 5.0f - dist;  // 2*DD = 5.0
        hingeL[t] = (dist < 5.0f) ? gap * gap : 0.f;
    }
    __syncthreads();
    if (t < 8) {
        float h = 0.f;
#pragma unroll
        for (int pr = 0; pr < 21; ++pr) h += hingeL[t * 21 + pr];
        distl[t] = h;
    }
    __syncthreads();
    if (t == 0) {
        float s = 0.f;
#pragma unroll
        for (int b = 0; b < 8; ++b)
            s += (varl[b] + distl[b] * (1.0f / 6.0f)) * (1.0f / 7.0f);
        out[0] = s * 0.125f;
    }
}

extern "C" void kernel_launch(void* const* d_in, const int* in_sizes, int n_in,
                              void* d_out, int out_size, void* d_ws, size_t ws_size,
                              hipStream_t stream) {
    const float* emb = (const float*)d_in[0];
    const int* lab = (const int*)d_in[1];
    float* out = (float*)d_out;
    float* ws = (float*)d_ws;

    // No memset needed: every ws slot is written before read each launch,
    // no atomic accumulation anywhere.
    k_pass1<<<NB * 16 * NC, 256, 0, stream>>>(emb, lab, ws);
    k_means<<<NB, 256, 0, stream>>>(ws);
    k_dist<<<NB * 256, 256, 0, stream>>>(emb, lab, ws);
    k_final<<<1, 256, 0, stream>>>(ws, out);
}

// Round 4
// 95.327 us; speedup vs baseline: 1.0861x; 1.0861x over previous
//
#include <hip/hip_runtime.h>

// Problem constants (fixed by reference setup_inputs)
#define HW 262144    // 512*512 pixels per image
#define NB 8         // batch
#define NC 32        // channels
#define NK 8         // num classes (NUM_IDS)

typedef float f4 __attribute__((ext_vector_type(4)));
typedef float v2f __attribute__((ext_vector_type(2)));

// fp8-path ws layout (bytes):
//   f8emb [8][32][262144] u8   @ 0          (67,108,864)
//   plab  [8][262144]     u8   @ 67,108,864 ( 2,097,152)
//   psum  [4096][8]       f32  @ 69,206,016 (   131,072)
//   pcnt  [128][8]        f32  @ 69,337,088 (     4,096)
//   meansT[8][32][8]      f32  @ 69,341,184 (     8,192)
//   counts[8][8]          f32  @ 69,349,376 (       256)
//   pdist [2048][8]       f32  @ 69,349,632 (    65,536)
#define OFF_F8   ((size_t)0)
#define OFF_PL   ((size_t)67108864)
#define OFF_PSUM ((size_t)69206016)
#define OFF_PCNT ((size_t)69337088)
#define OFF_MT   ((size_t)69341184)
#define OFF_CNT  ((size_t)69349376)
#define OFF_PD   ((size_t)69349632)
#define WS_NEED  ((size_t)69415168)

// ---------------------------------------------------------------------------
// Pass 1: per-class channel partial sums; optionally writes fp8 copy of emb
// and packed u8 labels. One block = (b, c, 16K-pixel chunk). Per-thread LDS
// slots (stride 9, coprime with 32 banks -> <=2-way, free). No atomics.
// b = f&7: XCD (heuristic f%8) owns one image -> label re-reads L2-hot.
// ---------------------------------------------------------------------------
template <bool FP8>
__global__ __launch_bounds__(256) void k_pass1(const float* __restrict__ emb,
                                               const int* __restrict__ lab,
                                               float* __restrict__ psum,
                                               float* __restrict__ pcnt,
                                               unsigned char* __restrict__ f8,
                                               unsigned char* __restrict__ plab) {
    __shared__ float slots[256 * 9];
    __shared__ float red[256];
    const int t = threadIdx.x;
    const int f = blockIdx.x;
    const int b = f & 7;
    const int o = f >> 3;        // 0..511 per image
    const int chunk = o >> 5;    // 0..15
    const int c = o & 31;

    float* myslot = &slots[t * 9];
#pragma unroll
    for (int i = 0; i < 9; ++i) myslot[i] = 0.f;

    const float* e = emb + ((size_t)(b * NC + c)) * HW;
    const int* lb = lab + (size_t)b * HW;
    unsigned char* f8c = FP8 ? (f8 + ((size_t)(b * NC + c)) * HW) : nullptr;
    const int base = chunk * 16384;

    for (int it = 0; it < 16; ++it) {
        const int p = base + it * 1024 + t * 4;
        const int4 l4 = *reinterpret_cast<const int4*>(lb + p);
        const f4 e4 = __builtin_nontemporal_load(reinterpret_cast<const f4*>(e + p));
        if (FP8) {
            int w = __builtin_amdgcn_cvt_pk_fp8_f32(e4.x, e4.y, 0, false);
            w = __builtin_amdgcn_cvt_pk_fp8_f32(e4.z, e4.w, w, true);
            *reinterpret_cast<int*>(f8c + p) = w;
        }
        myslot[l4.x] += e4.x;
        myslot[l4.y] += e4.y;
        myslot[l4.z] += e4.z;
        myslot[l4.w] += e4.w;
    }
    __syncthreads();

    {   // reduce slots[256][8] -> 8
        const int k = t & 7, r = t >> 3;
        float s = 0.f;
#pragma unroll
        for (int i = 0; i < 8; ++i) s += slots[(r + 32 * i) * 9 + k];
        red[r * 8 + k] = s;
    }
    __syncthreads();
    if (t < 8) {
        float s = 0.f;
#pragma unroll
        for (int r = 0; r < 32; ++r) s += red[r * 8 + t];
        psum[(size_t)f * 8 + t] = s;   // f encodes (b,c,chunk)
    }

    // counts (+ packed labels when FP8): only c==0 blocks; labels L2-hot
    if (c == 0) {
        __syncthreads();
#pragma unroll
        for (int i = 0; i < 9; ++i) myslot[i] = 0.f;
        for (int it = 0; it < 16; ++it) {
            const int p = base + it * 1024 + t * 4;
            const int4 l4 = *reinterpret_cast<const int4*>(lb + p);
            if (FP8) {
                const unsigned int pl = (unsigned)l4.x | ((unsigned)l4.y << 8) |
                                        ((unsigned)l4.z << 16) | ((unsigned)l4.w << 24);
                *reinterpret_cast<unsigned int*>(plab + (size_t)b * HW + p) = pl;
            }
            myslot[l4.x] += 1.f;
            myslot[l4.y] += 1.f;
            myslot[l4.z] += 1.f;
            myslot[l4.w] += 1.f;
        }
        __syncthreads();
        {
            const int k = t & 7, r = t >> 3;
            float s = 0.f;
#pragma unroll
            for (int i = 0; i < 8; ++i) s += slots[(r + 32 * i) * 9 + k];
            red[r * 8 + k] = s;
        }
        __syncthreads();
        if (t < 8) {
            float s = 0.f;
#pragma unroll
            for (int r = 0; r < 32; ++r) s += red[r * 8 + t];
            pcnt[(b * 16 + chunk) * 8 + t] = s;
        }
    }
}

// ---------------------------------------------------------------------------
// Reduce partials -> meansT [b][c][k] + counts [b][k]. 8 blocks, no atomics.
// ---------------------------------------------------------------------------
__global__ __launch_bounds__(256) void k_means(const float* __restrict__ psum,
                                               const float* __restrict__ pcnt,
                                               float* __restrict__ mt,
                                               float* __restrict__ cnt) {
    const int b = blockIdx.x;
    const int t = threadIdx.x;
    const int c = t >> 3, k = t & 7;

    float cn = 0.f;
#pragma unroll
    for (int ch = 0; ch < 16; ++ch) cn += pcnt[(b * 16 + ch) * 8 + k];

    float s = 0.f;
#pragma unroll
    for (int ch = 0; ch < 16; ++ch) s += psum[(size_t)(b + 8 * (c + 32 * ch)) * 8 + k];

    mt[b * 256 + c * 8 + k] = s / cn;
    if (c == 0) cnt[b * 8 + k] = cn;
}

// ---------------------------------------------------------------------------
// Pass 2 (fp8): per-pixel distance to class mean from the fp8 copy + packed
// labels (66 MB instead of 264 MB). Means in LDS transposed [c][k]: lanes
// hit 8 distinct banks, broadcast within bank -> conflict-free.
// ---------------------------------------------------------------------------
__global__ __launch_bounds__(256) void k_dist_fp8(const unsigned char* __restrict__ f8,
                                                  const unsigned char* __restrict__ plab,
                                                  const float* __restrict__ mt,
                                                  float* __restrict__ pd) {
    __shared__ float mT[256];
    __shared__ float slots[256 * 9];
    __shared__ float red[256];
    const int t = threadIdx.x;
    const int f = blockIdx.x;
    const int b = f & 7;
    const int chunk = f >> 3;  // 0..255

    mT[t] = mt[b * 256 + t];
    float* myslot = &slots[t * 9];
#pragma unroll
    for (int i = 0; i < 9; ++i) myslot[i] = 0.f;
    __syncthreads();

    const int p = chunk * 1024 + t * 4;
    const unsigned int lw = *reinterpret_cast<const unsigned int*>(plab + (size_t)b * HW + p);
    const int l0 = lw & 0xff, l1 = (lw >> 8) & 0xff, l2 = (lw >> 16) & 0xff, l3 = lw >> 24;
    const unsigned char* e8 = f8 + (size_t)b * NC * HW + p;

    float a0 = 0.f, a1 = 0.f, a2 = 0.f, a3 = 0.f;
#pragma unroll 8
    for (int c = 0; c < NC; ++c) {
        const unsigned int ew = *reinterpret_cast<const unsigned int*>(e8 + (size_t)c * HW);
        const v2f lo = __builtin_amdgcn_cvt_pk_f32_fp8(ew, false);
        const v2f hi = __builtin_amdgcn_cvt_pk_f32_fp8(ew, true);
        const float* mrow = &mT[c * 8];
        const float d0 = lo.x - mrow[l0];
        const float d1 = lo.y - mrow[l1];
        const float d2 = hi.x - mrow[l2];
        const float d3 = hi.y - mrow[l3];
        a0 += d0 * d0;
        a1 += d1 * d1;
        a2 += d2 * d2;
        a3 += d3 * d3;
    }
    myslot[l0] += sqrtf(a0);
    myslot[l1] += sqrtf(a1);
    myslot[l2] += sqrtf(a2);
    myslot[l3] += sqrtf(a3);
    __syncthreads();

    {
        const int k = t & 7, r = t >> 3;
        float s = 0.f;
#pragma unroll
        for (int i = 0; i < 8; ++i) s += slots[(r + 32 * i) * 9 + k];
        red[r * 8 + k] = s;
    }
    __syncthreads();
    if (t < 8) {
        float s = 0.f;
#pragma unroll
        for (int r = 0; r < 32; ++r) s += red[r * 8 + t];
        pd[(size_t)f * 8 + t] = s;
    }
}

// ---------------------------------------------------------------------------
// Pass 2 (fp32 fallback, used when ws too small for the fp8 copy).
// ---------------------------------------------------------------------------
__global__ __launch_bounds__(256) void k_dist_f32(const float* __restrict__ emb,
                                                  const int* __restrict__ lab,
                                                  const float* __restrict__ mt,
                                                  float* __restrict__ pd) {
    __shared__ float mT[256];
    __shared__ float slots[256 * 9];
    __shared__ float red[256];
    const int t = threadIdx.x;
    const int f = blockIdx.x;
    const int b = f & 7;
    const int chunk = f >> 3;

    mT[t] = mt[b * 256 + t];
    float* myslot = &slots[t * 9];
#pragma unroll
    for (int i = 0; i < 9; ++i) myslot[i] = 0.f;
    __syncthreads();

    const int p = chunk * 1024 + t * 4;
    const int4 l4 = *reinterpret_cast<const int4*>(lab + (size_t)b * HW + p);
    const float* e = emb + (size_t)b * NC * HW + p;

    float a0 = 0.f, a1 = 0.f, a2 = 0.f, a3 = 0.f;
#pragma unroll 8
    for (int c = 0; c < NC; ++c) {
        const f4 e4 = __builtin_nontemporal_load(reinterpret_cast<const f4*>(e + (size_t)c * HW));
        const float* mrow = &mT[c * 8];
        const float d0 = e4.x - mrow[l4.x];
        const float d1 = e4.y - mrow[l4.y];
        const float d2 = e4.z - mrow[l4.z];
        const float d3 = e4.w - mrow[l4.w];
        a0 += d0 * d0;
        a1 += d1 * d1;
        a2 += d2 * d2;
        a3 += d3 * d3;
    }
    myslot[l4.x] += sqrtf(a0);
    myslot[l4.y] += sqrtf(a1);
    myslot[l4.z] += sqrtf(a2);
    myslot[l4.w] += sqrtf(a3);
    __syncthreads();

    {
        const int k = t & 7, r = t >> 3;
        float s = 0.f;
#pragma unroll
        for (int i = 0; i < 8; ++i) s += slots[(r + 32 * i) * 9 + k];
        red[r * 8 + k] = s;
    }
    __syncthreads();
    if (t < 8) {
        float s = 0.f;
#pragma unroll
        for (int r = 0; r < 32; ++r) s += red[r * 8 + t];
        pd[(size_t)f * 8 + t] = s;
    }
}

// ---------------------------------------------------------------------------
// Epilogue: coalesced pdist reduce (lane-contiguous: thread t sums flat idx
// t, t+256, ...; residue mod 64 == b*8+k), then var + hinge, deterministic.
// ---------------------------------------------------------------------------
__global__ __launch_bounds__(256) void k_final(const float* __restrict__ pd,
                                               const float* __restrict__ cnt,
                                               const float* __restrict__ mt,
                                               float* __restrict__ out) {
    __shared__ float partial[256];
    __shared__ float distsum[64];   // [b][k]
    __shared__ float varl[8];
    __shared__ float hingeL[8 * 21];
    const int t = threadIdx.x;

    {
        float s = 0.f;
        for (int j = 0; j < 64; ++j) s += pd[(size_t)j * 256 + t];
        partial[t] = s;
    }
    __syncthreads();
    if (t < 64)
        distsum[t] = partial[t] + partial[t + 64] + partial[t + 128] + partial[t + 192];
    __syncthreads();

    if (t < 8) {
        float v = 0.f;
#pragma unroll
        for (int k = 1; k < 8; ++k)
            v += distsum[t * 8 + k] / cnt[t * 8 + k];
        varl[t] = v;
    }

    if (t < 168) {  // 8 images * 21 pairs among clusters 1..7
        const int b = t / 21;
        const int pr = t - b * 21;
        int ii = 1, jj = 2, c2 = 0;
        for (int a = 1; a <= 7; ++a)
            for (int bb = a + 1; bb <= 7; ++bb) {
                if (c2 == pr) { ii = a; jj = bb; }
                ++c2;
            }
        const float* mTb = mt + b * 256;
        float sq = 0.f;
#pragma unroll
        for (int c = 0; c < NC; ++c) {
            const float d = mTb[c * 8 + ii] - mTb[c * 8 + jj];
            sq += d * d;
        }
        const float dist = sqrtf(sq);
        const float gap = 5.0f - dist;  // 2*DD = 5.0
        hingeL[t] = (dist < 5.0f) ? gap * gap : 0.f;
    }
    __syncthreads();
    if (t == 0) {
        float s = 0.f;
#pragma unroll
        for (int b = 0; b < 8; ++b) {
            float h = 0.f;
            for (int pr = 0; pr < 21; ++pr) h += hingeL[b * 21 + pr];
            s += (varl[b] + h * (1.0f / 6.0f)) * (1.0f / 7.0f);
        }
        out[0] = s * 0.125f;
    }
}

extern "C" void kernel_launch(void* const* d_in, const int* in_sizes, int n_in,
                              void* d_out, int out_size, void* d_ws, size_t ws_size,
                              hipStream_t stream) {
    const float* emb = (const float*)d_in[0];
    const int* lab = (const int*)d_in[1];
    float* out = (float*)d_out;
    unsigned char* ws8 = (unsigned char*)d_ws;

    if (ws_size >= WS_NEED) {
        // fp8 second-pass path: 396 MB total HBM traffic vs 528 MB.
        unsigned char* f8 = ws8 + OFF_F8;
        unsigned char* pl = ws8 + OFF_PL;
        float* psum = (float*)(ws8 + OFF_PSUM);
        float* pcnt = (float*)(ws8 + OFF_PCNT);
        float* mt = (float*)(ws8 + OFF_MT);
        float* cnt = (float*)(ws8 + OFF_CNT);
        float* pd = (float*)(ws8 + OFF_PD);

        k_pass1<true><<<NB * 16 * NC, 256, 0, stream>>>(emb, lab, psum, pcnt, f8, pl);
        k_means<<<NB, 256, 0, stream>>>(psum, pcnt, mt, cnt);
        k_dist_fp8<<<NB * 256, 256, 0, stream>>>(f8, pl, mt, pd);
        k_final<<<1, 256, 0, stream>>>(pd, cnt, mt, out);
    } else {
        // fallback: fp32 re-read path (R1 structure)
        float* psum = (float*)ws8;                       // 32768 floats
        float* pcnt = psum + 32768;                      // 1024
        float* mt = pcnt + 1024;                         // 2048
        float* cnt = mt + 2048;                          // 64
        float* pd = cnt + 64;                            // 16384

        k_pass1<false><<<NB * 16 * NC, 256, 0, stream>>>(emb, lab, psum, pcnt, nullptr, nullptr);
        k_means<<<NB, 256, 0, stream>>>(psum, pcnt, mt, cnt);
        k_dist_f32<<<NB * 256, 256, 0, stream>>>(emb, lab, mt, pd);
        k_final<<<1, 256, 0, stream>>>(pd, cnt, mt, out);
    }
}